// Round 1
// baseline (839.047 us; speedup 1.0000x reference)
//
#include <hip/hip_runtime.h>
#include <math.h>

#define NN 100000
#define NE 1600000
#define ET (NN + NE)
#define D 64
#define EDIM 16

static __device__ __forceinline__ float leaky(float a) { return a >= 0.f ? a : 0.2f * a; }

// K0: deg[i]=1 (self loop), meansum=0, block0 computes w16[l*16+k] = dot(W_e[l][k][:], a_e[l][:])
__global__ __launch_bounds__(256) void k_init(int* __restrict__ deg, float* __restrict__ meansum,
                                              float* __restrict__ w16, const float* __restrict__ We,
                                              const float* __restrict__ ae) {
    int i = blockIdx.x * 256 + threadIdx.x;
    if (i < NN) deg[i] = 1;
    if (blockIdx.x == 0) {
        int t = threadIdx.x;
        if (t < 16) meansum[t] = 0.f;
        if (t < 48) {
            int l = t >> 4, k = t & 15;
            const float* wr = We + l * (EDIM * D) + k * D;
            const float* av = ae + l * D;
            float s = 0.f;
#pragma unroll
            for (int j = 0; j < D; j++) s += wr[j] * av[j];
            w16[t] = s;
        }
    }
}

// K1: histogram of dst, s_edge for all 3 layers, column-sum of edge_attr (for self-loop mean)
__global__ __launch_bounds__(256) void k_edge(const int* __restrict__ ei, const float* __restrict__ ea,
                                              const float* __restrict__ w16, int* __restrict__ deg,
                                              float* __restrict__ sedge3, float* __restrict__ meansum) {
    int tid = blockIdx.x * blockDim.x + threadIdx.x;
    int stride = gridDim.x * blockDim.x;
    float wr[48];
#pragma unroll
    for (int c = 0; c < 48; c++) wr[c] = w16[c];
    float ms[16];
#pragma unroll
    for (int c = 0; c < 16; c++) ms[c] = 0.f;
    for (int e = tid; e < NE; e += stride) {
        int d = ei[NE + e];
        atomicAdd(&deg[d], 1);
        const float4* ea4 = (const float4*)(ea + (size_t)e * EDIM);
        float4 v0 = ea4[0], v1 = ea4[1], v2 = ea4[2], v3 = ea4[3];
        float vv[16] = {v0.x, v0.y, v0.z, v0.w, v1.x, v1.y, v1.z, v1.w,
                        v2.x, v2.y, v2.z, v2.w, v3.x, v3.y, v3.z, v3.w};
#pragma unroll
        for (int c = 0; c < 16; c++) ms[c] += vv[c];
#pragma unroll
        for (int l = 0; l < 3; l++) {
            float s = 0.f;
#pragma unroll
            for (int c = 0; c < 16; c++) s += vv[c] * wr[l * 16 + c];
            sedge3[(size_t)l * NE + e] = s;
        }
    }
    // reduce ms: wave shuffle -> LDS -> one global atomic set per block
#pragma unroll
    for (int c = 0; c < 16; c++)
        for (int o = 32; o; o >>= 1) ms[c] += __shfl_xor(ms[c], o);
    __shared__ float bsum[16];
    if (threadIdx.x < 16) bsum[threadIdx.x] = 0.f;
    __syncthreads();
    if ((threadIdx.x & 63) == 0)
        for (int c = 0; c < 16; c++) atomicAdd(&bsum[c], ms[c]);
    __syncthreads();
    if (threadIdx.x < 16) atomicAdd(&meansum[threadIdx.x], bsum[threadIdx.x]);
}

// K2a: per-block exclusive scan of deg
__global__ __launch_bounds__(256) void k_scan1(const int* __restrict__ deg, int* __restrict__ rowstart,
                                               int* __restrict__ blocksum) {
    __shared__ int sd[256];
    int t = threadIdx.x;
    int i = blockIdx.x * 256 + t;
    int v = (i < NN) ? deg[i] : 0;
    sd[t] = v;
    __syncthreads();
    for (int o = 1; o < 256; o <<= 1) {
        int x = sd[t];
        int y = (t >= o) ? sd[t - o] : 0;
        __syncthreads();
        sd[t] = x + y;
        __syncthreads();
    }
    int incl = sd[t];
    if (i < NN) rowstart[i] = incl - v;
    if (t == 255) blocksum[blockIdx.x] = incl;
}

// K2b: scan block sums; also finalize rowstart[N], self-loop scores slw[l]
__global__ __launch_bounds__(512) void k_scan2(const int* __restrict__ blocksum, int* __restrict__ blockoff,
                                               int* __restrict__ rowstart, const float* __restrict__ meansum,
                                               const float* __restrict__ w16, float* __restrict__ slw, int nb) {
    __shared__ int sd[512];
    int t = threadIdx.x;
    int v = (t < nb) ? blocksum[t] : 0;
    sd[t] = v;
    __syncthreads();
    for (int o = 1; o < 512; o <<= 1) {
        int x = sd[t];
        int y = (t >= o) ? sd[t - o] : 0;
        __syncthreads();
        sd[t] = x + y;
        __syncthreads();
    }
    if (t < nb) blockoff[t] = sd[t] - v;
    if (t == 0) rowstart[NN] = ET;
    if (t < 3) {
        float s = 0.f;
        for (int k = 0; k < 16; k++) s += (meansum[k] * (1.0f / NE)) * w16[t * 16 + k];
        slw[t] = s;
    }
}

// K2c: add block offsets, init cursor
__global__ __launch_bounds__(256) void k_scan3(int* __restrict__ rowstart, const int* __restrict__ blockoff,
                                               int* __restrict__ cursor) {
    int i = blockIdx.x * 256 + threadIdx.x;
    if (i < NN) {
        int r = rowstart[i] + blockoff[i >> 8];
        rowstart[i] = r;
        cursor[i] = r;
    }
}

// K3: scatter edges (+self loops) into CSR records {src, se_l0, se_l1, se_l2}
__global__ __launch_bounds__(256) void k_scatter(const int* __restrict__ ei, const float* __restrict__ sedge3,
                                                 const float* __restrict__ slw, int* __restrict__ cursor,
                                                 float4* __restrict__ csr) {
    int tid = blockIdx.x * blockDim.x + threadIdx.x;
    int stride = gridDim.x * blockDim.x;
    float s0 = slw[0], s1 = slw[1], s2 = slw[2];
    for (int e = tid; e < ET; e += stride) {
        int s, d;
        float a0, a1, a2;
        if (e < NE) {
            s = ei[e];
            d = ei[NE + e];
            a0 = sedge3[e];
            a1 = sedge3[(size_t)NE + e];
            a2 = sedge3[2 * (size_t)NE + e];
        } else {
            s = d = e - NE;
            a0 = s0; a1 = s1; a2 = s2;
        }
        int pos = atomicAdd(&cursor[d], 1);
        csr[pos] = make_float4(__int_as_float(s), a0, a1, a2);
    }
}

// GEMM: h = x @ W  (+ s_src = h@a_src, s_dst = h@a_dst). lane = output column.
__global__ __launch_bounds__(256) void k_gemm(const float* __restrict__ x, const float* __restrict__ W,
                                              const float* __restrict__ asrc, const float* __restrict__ adst,
                                              float* __restrict__ h, float* __restrict__ ssrc,
                                              float* __restrict__ sdst) {
    int t = threadIdx.x;
    int lane = t & 63;
    int wv = __builtin_amdgcn_readfirstlane(t >> 6);
    int row0 = blockIdx.x * 64 + wv * 16;
    float Wreg[64];
#pragma unroll
    for (int k = 0; k < 64; k++) Wreg[k] = W[k * 64 + lane];
    float asl = asrc[lane], adl = adst[lane];
    for (int rr = 0; rr < 16; rr++) {
        int r = row0 + rr;
        if (r >= NN) break;
        const float* xr = x + (size_t)r * 64;
        float acc = 0.f;
#pragma unroll
        for (int k = 0; k < 64; k++) acc = fmaf(xr[k], Wreg[k], acc);
        h[(size_t)r * 64 + lane] = acc;
        float ps = acc * asl, pd = acc * adl;
#pragma unroll
        for (int o = 32; o; o >>= 1) {
            ps += __shfl_xor(ps, o);
            pd += __shfl_xor(pd, o);
        }
        if (lane == 0) {
            ssrc[r] = ps;
            sdst[r] = pd;
        }
    }
}

// Aggregation: one wave per node. Softmax over incoming edges with deferred normalization,
// acc[d] += w_j * h[src_j][d]; epilogue: /z + bias, exact GELU.
template <int LAYER>
__global__ __launch_bounds__(256) void k_agg(const float4* __restrict__ csr, const int* __restrict__ rowstart,
                                             const float* __restrict__ ssrc, const float* __restrict__ sdst,
                                             const float* __restrict__ h, const float* __restrict__ bias,
                                             float* __restrict__ out) {
    int t = threadIdx.x;
    int lane = t & 63;
    int wv = __builtin_amdgcn_readfirstlane(t >> 6);
    int n = blockIdx.x * 4 + wv;  // NN % 4 == 0, always valid
    int start = rowstart[n];
    int dg = rowstart[n + 1] - start;
    float sd = sdst[n];
    // pass A: running max of leaky(alpha)
    float m = -1e30f;
    for (int i = lane; i < dg; i += 64) {
        float4 rec = csr[start + i];
        float se = (LAYER == 0) ? rec.y : ((LAYER == 1) ? rec.z : rec.w);
        int s = __float_as_int(rec.x);
        m = fmaxf(m, leaky(ssrc[s] + sd + se));
    }
#pragma unroll
    for (int o = 32; o; o >>= 1) m = fmaxf(m, __shfl_xor(m, o));
    // pass B: exp, accumulate weighted h rows (normalize at the end)
    float acc = 0.f, z = 0.f;
    for (int base = 0; base < dg; base += 64) {
        int i = base + lane;
        float ew = 0.f;
        int es = 0;
        if (i < dg) {
            float4 rec = csr[start + i];
            float se = (LAYER == 0) ? rec.y : ((LAYER == 1) ? rec.z : rec.w);
            es = __float_as_int(rec.x);
            ew = __expf(leaky(ssrc[es] + sd + se) - m);
        }
        z += ew;
        int cnt = min(64, dg - base);
        for (int j = 0; j < cnt; j++) {
            float wj = __shfl(ew, j);
            int sj = __shfl(es, j);
            acc = fmaf(wj, h[(size_t)sj * 64 + lane], acc);
        }
    }
#pragma unroll
    for (int o = 32; o; o >>= 1) z += __shfl_xor(z, o);
    float v = acc / z + bias[lane];
    float g = 0.5f * v * (1.0f + erff(v * 0.70710678118654752f));
    out[(size_t)n * 64 + lane] = g;
}

extern "C" void kernel_launch(void* const* d_in, const int* in_sizes, int n_in,
                              void* d_out, int out_size, void* d_ws, size_t ws_size,
                              hipStream_t stream) {
    const float* x0 = (const float*)d_in[0];
    const int* ei = (const int*)d_in[1];
    const float* ea = (const float*)d_in[2];
    const float* Ws = (const float*)d_in[3];
    const float* asrc = (const float*)d_in[4];
    const float* adst = (const float*)d_in[5];
    const float* We = (const float*)d_in[6];
    const float* ae = (const float*)d_in[7];
    const float* bias = (const float*)d_in[8];

    char* wsb = (char*)d_ws;
    size_t off = 0;
    auto alloc = [&](size_t bytes) -> char* {
        char* p = wsb + off;
        off += (bytes + 255) & ~(size_t)255;
        return p;
    };
    float* xA = (float*)alloc((size_t)NN * D * 4);
    float* xB = (float*)alloc((size_t)NN * D * 4);
    float* h = (float*)alloc((size_t)NN * D * 4);
    float* ssrc = (float*)alloc((size_t)NN * 4);
    float* sdst = (float*)alloc((size_t)NN * 4);
    float* sedge3 = (float*)alloc(3 * (size_t)NE * 4);
    float4* csr = (float4*)alloc((size_t)ET * 16);
    int* deg = (int*)alloc((size_t)NN * 4);
    int* rowstart = (int*)alloc((size_t)(NN + 1) * 4);
    int* cursor = (int*)alloc((size_t)NN * 4);
    int* blocksum = (int*)alloc(512 * 4);
    int* blockoff = (int*)alloc(512 * 4);
    float* meansum = (float*)alloc(16 * 4);
    float* w16 = (float*)alloc(48 * 4);
    float* slw = (float*)alloc(3 * 4);

    int nb = (NN + 255) / 256;  // 391
    k_init<<<nb, 256, 0, stream>>>(deg, meansum, w16, We, ae);
    k_edge<<<1024, 256, 0, stream>>>(ei, ea, w16, deg, sedge3, meansum);
    k_scan1<<<nb, 256, 0, stream>>>(deg, rowstart, blocksum);
    k_scan2<<<1, 512, 0, stream>>>(blocksum, blockoff, rowstart, meansum, w16, slw, nb);
    k_scan3<<<nb, 256, 0, stream>>>(rowstart, blockoff, cursor);
    k_scatter<<<2048, 256, 0, stream>>>(ei, sedge3, slw, cursor, csr);

    float* outp = (float*)d_out;
    int gg = (NN + 63) / 64;
    // layer 0
    k_gemm<<<gg, 256, 0, stream>>>(x0, Ws, asrc, adst, h, ssrc, sdst);
    k_agg<0><<<NN / 4, 256, 0, stream>>>(csr, rowstart, ssrc, sdst, h, bias, xA);
    // layer 1
    k_gemm<<<gg, 256, 0, stream>>>(xA, Ws + 4096, asrc + 64, adst + 64, h, ssrc, sdst);
    k_agg<1><<<NN / 4, 256, 0, stream>>>(csr, rowstart, ssrc, sdst, h, bias + 64, xB);
    // layer 2
    k_gemm<<<gg, 256, 0, stream>>>(xB, Ws + 8192, asrc + 128, adst + 128, h, ssrc, sdst);
    k_agg<2><<<NN / 4, 256, 0, stream>>>(csr, rowstart, ssrc, sdst, h, bias + 128, outp);
}